// Round 11
// baseline (237.853 us; speedup 1.0000x reference)
//
#include <hip/hip_runtime.h>
#include <math.h>

// Problem constants (fixed by setup_inputs): B=2, C=19, H=W=512, fp32 in/out.
constexpr int H = 512, W = 512, B = 2;
constexpr int HW = H * W;

typedef __attribute__((ext_vector_type(8))) short short8;
typedef __attribute__((ext_vector_type(4))) float floatx4;
typedef __attribute__((ext_vector_type(4))) unsigned int uint4v;

__device__ inline unsigned short f2bf(float f) {
  union { float f; unsigned int u; } x{f};
  const unsigned int u = x.u;
  return (unsigned short)((u + 0x7FFFu + ((u >> 16) & 1u)) >> 16);
}
__device__ inline float bf2f(unsigned short s) {
  union { unsigned int u; float f; } x;
  x.u = (unsigned int)s << 16;
  return x.f;
}
// unpack packed bf16 pair (one dword) -> two floats
__device__ inline void unpk2(unsigned int u, float& lo, float& hi) {
  union { unsigned int u; float f; } a, b;
  a.u = u << 16;
  b.u = u & 0xffff0000u;
  lo = a.f;
  hi = b.f;
}

// 3-wide row load for 1-px stencils: r[1] = col w.
__device__ inline void load_row3(const float* __restrict__ plane, int hh,
                                 int w, float r[3]) {
  r[0] = 0.f; r[1] = 0.f; r[2] = 0.f;
  if ((unsigned)hh < (unsigned)H) {
    const float* rp = plane + (size_t)hh * W + w;
    r[1] = rp[0];
    if (w > 0) r[0] = rp[-1];
    if (w + 1 < W) r[2] = rp[1];
  }
}

// ---------------------------------------------------------------------------
// fp32 tiled 3x3 conv 3->16, writes bf16 NHWC packed output [B][H][W][16].
// ---------------------------------------------------------------------------
template <int CIN, int COUT, bool RELU>
__global__ __launch_bounds__(256) void conv3x3_fp32_pack(
    const float* __restrict__ in0, const float* __restrict__ wgt,
    const float* __restrict__ bias, unsigned short* __restrict__ outp) {
  constexpr int TS = 16, TH = 18, LDW = 20;
  __shared__ float tile[CIN][TH][LDW];
  const int tx = threadIdx.x, ty = threadIdx.y;
  const int tid = ty * 16 + tx;
  const int w0 = blockIdx.x * TS, h0 = blockIdx.y * TS, b = blockIdx.z;

  for (int idx = tid; idx < CIN * TH * TH; idx += 256) {
    const int cin = idx / (TH * TH);
    const int rem = idx - cin * (TH * TH);
    const int r = rem / TH, c = rem - r * TH;
    const int gh = h0 + r - 1, gw = w0 + c - 1;
    float v = 0.f;
    if ((unsigned)gh < (unsigned)H && (unsigned)gw < (unsigned)W)
      v = in0[(size_t)(b * CIN + cin) * HW + gh * W + gw];
    tile[cin][r][c] = v;
  }
  __syncthreads();

  float acc[COUT];
#pragma unroll
  for (int co = 0; co < COUT; ++co) acc[co] = bias[co];
  for (int cin = 0; cin < CIN; ++cin) {
#pragma unroll
    for (int t = 0; t < 9; ++t) {
      const int ky = t / 3, kx = t - ky * 3;
      const float v = tile[cin][ty + ky][tx + kx];
#pragma unroll
      for (int co = 0; co < COUT; ++co)
        acc[co] = fmaf(v, wgt[(co * CIN + cin) * 9 + t], acc[co]);
    }
  }
  const int oh = h0 + ty, ow = w0 + tx;
  unsigned int pk[COUT / 2];
#pragma unroll
  for (int c2 = 0; c2 < COUT / 2; ++c2) {
    float a0 = acc[2 * c2], a1 = acc[2 * c2 + 1];
    if (RELU) { a0 = fmaxf(a0, 0.f); a1 = fmaxf(a1, 0.f); }
    pk[c2] = (unsigned)f2bf(a0) | ((unsigned)f2bf(a1) << 16);
  }
  unsigned short* dst = outp + ((size_t)(b * H + oh) * W + ow) * COUT;
#pragma unroll
  for (int u = 0; u < COUT / 8; ++u)
    *(uint4v*)(dst + u * 8) = uint4v{pk[u * 4], pk[u * 4 + 1], pk[u * 4 + 2], pk[u * 4 + 3]};
}

// ---------------------------------------------------------------------------
// Weight repack into B-fragment order for mfma_f32_16x16x32_bf16.
// k = tap*CINP + cin (CINP mult of 8 so 8-runs stay within one tap).
// 3 launches merged into one kernel (round-7, ~3 us/dispatch boundary).
// ---------------------------------------------------------------------------
template <int CIN, int CINP, int COUT, int KS>
__device__ inline void repack_body(int idx, const float* __restrict__ w,
                                   unsigned short* __restrict__ bp) {
  constexpr int NT = COUT / 16;
  if (idx >= NT * KS * 512) return;
  const int j = idx & 7;
  const int l = (idx >> 3) & 63;
  const int ks = (idx >> 9) % KS;
  const int nt = idx / (KS * 512);
  const int co = nt * 16 + (l & 15);
  const int kglob = ks * 32 + (l >> 4) * 8 + j;
  const int tap = kglob / CINP;
  const int cin = kglob % CINP;
  float v = 0.f;
  if (tap < 9 && cin < CIN) v = w[((size_t)co * CIN + cin) * 9 + tap];
  bp[idx] = f2bf(v);
}

__global__ __launch_bounds__(256) void repack_all(
    const float* __restrict__ iw2, const float* __restrict__ gw1,
    const float* __restrict__ gw2, unsigned short* __restrict__ bp_ic2,
    unsigned short* __restrict__ bp_gc1, unsigned short* __restrict__ bp_gc2) {
  const int blk = blockIdx.x, tid = threadIdx.x;
  if (blk < 10) {
    repack_body<16, 16, 16, 5>(blk * 256 + tid, iw2, bp_ic2);
  } else if (blk < 38) {
    repack_body<20, 24, 32, 7>((blk - 10) * 256 + tid, gw1, bp_gc1);
  } else {
    repack_body<32, 32, 32, 9>((blk - 38) * 256 + tid, gw2, bp_gc2);
  }
}

// ---------------------------------------------------------------------------
// Implicit-GEMM 3x3 conv via bf16 MFMA. Packed bf16 NHWC input [H][W][CINP].
// Tile = 32x8 px, 4 waves x 2 rows; 2048 blocks.
// EPI=0: packed bf16 NHWC output (bias+relu, direct scalar stores). unused.
// EPI=1: fused 1x1 16->19 (intra head) -> packed [H][W][24] (ch19..23=0).
// EPI=4: like EPI=0 but via LDS bounce + dwordx4 coalesced stores (round-10;
//        the direct path was 32 scalar 2B stores/thread).
// EPI=3: fused 1x1 32->11 + sigmoid + normalize -> gfo, + fused combine.
//        Round-10 x-stage: two-phase with a compiler memory barrier --
//        Phase A issues all 26 predicated loads into regs, the asm clobber
//        pins them (round-9's plain prefetch was SUNK by regalloc: VGPR
//        stayed 68), the 1x1 VALU work hides the latency, Phase B is pure
//        reg->LDS. xs layout is tap-major [r][col][22 fp32] so combine reads
//        channels as float2 pairs (90 LDS insts vs 171 scalar; stride 22 =
//        2-way bank = free). Per-channel FMA order unchanged -> bit-identical.
// EDGE19: edg = argmax map sx; inline 3x3 Laplacian during staging, written
//        to LDS ch19 and the edge output plane (halo rewrites benign).
// ---------------------------------------------------------------------------
template <int CINP, int KS, int NT, bool EDGE19, int EPI>
__global__ __launch_bounds__(256) void conv3x3_mfma(
    const unsigned short* __restrict__ inp, const float* __restrict__ edg,
    const unsigned short* __restrict__ bpack, const float* __restrict__ bias,
    const float* __restrict__ ew, const float* __restrict__ eb,
    unsigned short* __restrict__ outp, float* __restrict__ outf,
    const float* __restrict__ xin, const unsigned short* __restrict__ ipn,
    float* __restrict__ outc) {
  constexpr int COUT = NT * 16;
  constexpr int CS = (CINP == 16) ? 24 : 40;  // LDS cin stride (16B mult)
  constexpr int EPS = (EPI == 1) ? 24 : 40;   // epilogue LDS px stride
  constexpr int TR = 10;                      // 8 rows + halo
  constexpr int XN = 19 * 10 * 34;            // x stencil window elems (6460)
  constexpr int XIT = (XN + 255) / 256;       // 26 per-thread loads
  constexpr int CPC = 22;                     // xs channel-stride (dwords)
  // EPI=3 needs 340*22 dwords = 29920 B for the tap-major xs view.
  constexpr int CSX = (EPI == 3) ? 44 : CS;
  __shared__ __align__(16) unsigned short tile[TR * 34 * CSX];

  const int tid = threadIdx.x;
  const int w0 = blockIdx.x * 32, h0 = blockIdx.y * 8, b = blockIdx.z;

  // ---- stage halo'd tile: packed pixel copy (dwordx4), zero for OOB ----
  for (int idx = tid; idx < TR * 34; idx += 256) {
    const int r = idx / 34, c = idx - r * 34;
    const int gh = h0 + r - 1, gw = w0 + c - 1;
    unsigned short* dst = tile + (size_t)(r * 34 + c) * CS;
    if ((unsigned)gh < (unsigned)H && (unsigned)gw < (unsigned)W) {
      const unsigned short* src = inp + ((size_t)(b * H + gh) * W + gw) * CINP;
#pragma unroll
      for (int u = 0; u < CINP / 8; ++u)
        *(uint4v*)(dst + u * 8) = *(const uint4v*)(src + u * 8);
      if (EDGE19) {
        // inline Laplacian of the argmax map (exact integer fp32 sums)
        const float* sp = edg + (size_t)b * HW;
        float r0[3], r1[3], r2[3];
        load_row3(sp, gh - 1, gw, r0);
        load_row3(sp, gh, gw, r1);
        load_row3(sp, gh + 1, gw, r2);
        const float e = r0[0] + r0[1] + r0[2] + r1[0] + r1[2] + r2[0] +
                        r2[1] + r2[2] - 8.f * r1[1];
        dst[19] = f2bf(e);
        outf[(size_t)b * HW + (size_t)gh * W + gw] = e;
      }
    } else {
#pragma unroll
      for (int u = 0; u < CINP / 8; ++u)
        *(uint4v*)(dst + u * 8) = uint4v{0, 0, 0, 0};
    }
  }
  __syncthreads();

  // ---- K-loop (fully unrolled) ----
  const int wv = tid >> 6, lane = tid & 63;
  const int q = lane >> 4, l15 = lane & 15;
  const int rb = wv * 2;

  floatx4 acc[4][NT];
#pragma unroll
  for (int mf = 0; mf < 4; ++mf)
#pragma unroll
    for (int nt = 0; nt < NT; ++nt) acc[mf][nt] = floatx4{0.f, 0.f, 0.f, 0.f};

#pragma unroll
  for (int ks = 0; ks < KS; ++ks) {
    short8 bfrag[NT];
#pragma unroll
    for (int nt = 0; nt < NT; ++nt)
      bfrag[nt] = *(const short8*)(bpack + (size_t)(((nt * KS) + ks) * 64 + lane) * 8);

    const int kbase = ks * 32;  // compile-time
    const int kq = kbase + q * 8;
    int tapq = kq / CINP;
    const int cinq = kq % CINP;
    if (tapq > 8) tapq = 8;  // zero-weight pad region
    const int ky = tapq / 3, kx = tapq - ky * 3;
    const unsigned short* aptr =
        tile + (size_t)((rb + ky) * 34 + (l15 + kx)) * CS + cinq;

#pragma unroll
    for (int mf = 0; mf < 4; ++mf) {
      constexpr int mfs[4][2] = {{0, 0}, {0, 16}, {1, 0}, {1, 16}};
      const int off = (mfs[mf][0] * 34 + mfs[mf][1]) * CS;
      const short8 af = *(const short8*)(aptr + off);
#pragma unroll
      for (int nt = 0; nt < NT; ++nt)
        acc[mf][nt] = __builtin_amdgcn_mfma_f32_16x16x32_bf16(
            af, bfrag[nt], acc[mf][nt], 0, 0, 0);
    }
  }

  if constexpr (EPI == 0) {
    // ---- direct bf16 short stores from C-layout registers ----
#pragma unroll
    for (int nt = 0; nt < NT; ++nt) {
      const float bv = bias[nt * 16 + l15];
#pragma unroll
      for (int mf = 0; mf < 4; ++mf) {
        const int row = mf >> 1, colb = (mf & 1) * 16 + q * 4;
        unsigned short* dst =
            outp + ((size_t)(b * H + h0 + rb + row) * W + w0) * COUT + nt * 16 + l15;
#pragma unroll
        for (int rg = 0; rg < 4; ++rg) {
          const float v = fmaxf(acc[mf][nt][rg] + bv, 0.f);
          dst[(size_t)(colb + rg) * COUT] = f2bf(v);
        }
      }
    }
  } else {
    // ---- fused epilogue: conv out (bias+relu, bf16) -> LDS bounce ----
    __syncthreads();  // all waves done reading the staging tile
#pragma unroll
    for (int nt = 0; nt < NT; ++nt) {
      const float bv = bias[nt * 16 + l15];
#pragma unroll
      for (int mf = 0; mf < 4; ++mf) {
        const int row = rb + (mf >> 1), colb = (mf & 1) * 16 + q * 4;
#pragma unroll
        for (int rg = 0; rg < 4; ++rg) {
          const int px = row * 32 + colb + rg;
          tile[(size_t)px * EPS + nt * 16 + l15] =
              f2bf(fmaxf(acc[mf][nt][rg] + bv, 0.f));
        }
      }
    }
    __syncthreads();

    {
      const int p = tid;                       // 256 px per tile, 1/thread
      const int gh = h0 + (p >> 5), gw = w0 + (p & 31);
      const unsigned short* src = tile + (size_t)p * EPS;

      if constexpr (EPI == 4) {
        // coalesced copy-out: LDS [px][40] -> packed [H][W][32]
        unsigned short* dst = outp + ((size_t)(b * H + gh) * W + gw) * 32;
#pragma unroll
        for (int u = 0; u < 4; ++u)
          *(uint4v*)(dst + u * 8) = *(const uint4v*)(src + u * 8);
      } else if constexpr (EPI == 1) {
        // 1x1 conv 16->19 (no relu), pack to [H][W][24] (ch19..23 = 0)
        float xi[16];
        const uint4v r0 = *(const uint4v*)src;
        const uint4v r1 = *(const uint4v*)(src + 8);
        unpk2(r0.x, xi[0], xi[1]);   unpk2(r0.y, xi[2], xi[3]);
        unpk2(r0.z, xi[4], xi[5]);   unpk2(r0.w, xi[6], xi[7]);
        unpk2(r1.x, xi[8], xi[9]);   unpk2(r1.y, xi[10], xi[11]);
        unpk2(r1.z, xi[12], xi[13]); unpk2(r1.w, xi[14], xi[15]);
        float a[19];
#pragma unroll
        for (int co = 0; co < 19; ++co) a[co] = eb[co];
#pragma unroll
        for (int c = 0; c < 16; ++c) {
          const float v = xi[c];
#pragma unroll
          for (int co = 0; co < 19; ++co) a[co] = fmaf(v, ew[co * 16 + c], a[co]);
        }
        unsigned int pk[12];
#pragma unroll
        for (int j = 0; j < 9; ++j)
          pk[j] = (unsigned)f2bf(a[2 * j]) | ((unsigned)f2bf(a[2 * j + 1]) << 16);
        pk[9] = (unsigned)f2bf(a[18]);
        pk[10] = 0; pk[11] = 0;
        unsigned short* dst = outp + ((size_t)(b * H + gh) * W + gw) * 24;
#pragma unroll
        for (int u = 0; u < 3; ++u)
          *(uint4v*)(dst + u * 8) =
              uint4v{pk[u * 4], pk[u * 4 + 1], pk[u * 4 + 2], pk[u * 4 + 3]};
      } else {
        // EPI==3: 1x1 conv 32->11 + sigmoid + normalize + fused combine
        float xi[32];
#pragma unroll
        for (int u = 0; u < 4; ++u) {
          const uint4v r = *(const uint4v*)(src + u * 8);
          unpk2(r.x, xi[u * 8 + 0], xi[u * 8 + 1]);
          unpk2(r.y, xi[u * 8 + 2], xi[u * 8 + 3]);
          unpk2(r.z, xi[u * 8 + 4], xi[u * 8 + 5]);
          unpk2(r.w, xi[u * 8 + 6], xi[u * 8 + 7]);
        }
        __syncthreads();  // conv-out read; tile now dead

        // ---- Phase A: issue ALL x-window loads (predicated) ----
        float xr[XIT];
#pragma unroll
        for (int i = 0; i < XIT; ++i) {
          const int idx = tid + i * 256;
          float v = 0.f;
          if (idx < XN) {
            const int c = idx / 340;
            const int rem = idx - c * 340;
            const int r = rem / 34, col = rem - r * 34;
            const int gh2 = h0 + r - 1, gw2 = w0 + col - 1;
            if ((unsigned)gh2 < (unsigned)H && (unsigned)gw2 < (unsigned)W)
              v = xin[(size_t)(b * 19 + c) * HW + (size_t)gh2 * W + gw2];
          }
          xr[i] = v;
        }
        // pin the loads here; 1x1 VALU below interleaves under their latency
        asm volatile("" ::: "memory");

        float g[11], sum = 0.f;
#pragma unroll
        for (int co = 0; co < 11; ++co) {
          float a = eb[co];
#pragma unroll
          for (int c = 0; c < 32; ++c) a = fmaf(xi[c], ew[co * 32 + c], a);
          g[co] = 1.f / (1.f + expf(-a));
          sum += g[co];
        }
        const float inv = 1.f / (sum + 1e-9f);
        const size_t s = (size_t)gh * W + gw;
#pragma unroll
        for (int co = 0; co < 11; ++co)
          outf[(size_t)(b * 11 + co) * HW + s] = g[co] * inv;

        // ---- Phase B: regs -> tap-major LDS xs[r][col][CPC] ----
        float* xs = (float*)tile;
#pragma unroll
        for (int i = 0; i < XIT; ++i) {
          const int idx = tid + i * 256;
          if (idx < XN) {
            const int c = idx / 340;
            const int rem = idx - c * 340;
            const int r = rem / 34, col = rem - r * 34;
            xs[(r * 34 + col) * CPC + c] = xr[i];
          }
        }
        __syncthreads();

        // ---- combine: tap-major float2 reads, FMA order preserved ----
        float gn[11];
#pragma unroll
        for (int m = 0; m < 11; ++m) gn[m] = g[m] * inv;
        const int pr = p >> 5, pc = p & 31;

        // taps in original accumulation order: center, then 8 neighbors
        constexpr int taps[9][3] = {{1, 1, 0}, {0, 0, 1}, {0, 1, 2},
                                    {0, 2, 3}, {1, 0, 4}, {1, 2, 5},
                                    {2, 0, 6}, {2, 1, 7}, {2, 2, 8}};
        float a[19];
#pragma unroll
        for (int t = 0; t < 9; ++t) {
          const float gv = gn[taps[t][2]];
          const float* xp =
              xs + ((pr + taps[t][0]) * 34 + (pc + taps[t][1])) * CPC;
#pragma unroll
          for (int j = 0; j < 9; ++j) {
            const float2 v = *(const float2*)(xp + 2 * j);
            if (t == 0) {
              a[2 * j] = gv * v.x;
              a[2 * j + 1] = gv * v.y;
            } else {
              a[2 * j] = fmaf(gv, v.x, a[2 * j]);
              a[2 * j + 1] = fmaf(gv, v.y, a[2 * j + 1]);
            }
          }
          if (t == 0) a[18] = gv * xp[18];
          else a[18] = fmaf(gv, xp[18], a[18]);
        }
        // intra tap (gn[10]) from packed bf16 [H][W][24]: 3 vector loads
        const unsigned short* ip = ipn + ((size_t)b * HW + s) * 24;
        const uint4v i0 = *(const uint4v*)ip;
        const uint4v i1 = *(const uint4v*)(ip + 8);
        const uint4v i2 = *(const uint4v*)(ip + 16);
        unsigned short itv[24];
        *(uint4v*)itv = i0; *(uint4v*)(itv + 8) = i1; *(uint4v*)(itv + 16) = i2;
#pragma unroll
        for (int c = 0; c < 19; ++c) {
          a[c] = fmaf(gn[10], bf2f(itv[c]), a[c]);
          outc[(size_t)(b * 19 + c) * HW + s] = a[c];
        }
      }
    }
  }
}

// ---------------------------------------------------------------------------
// argmax over 19 channels -> float index, 1 pixel/thread.
// ---------------------------------------------------------------------------
__global__ __launch_bounds__(256) void argmax_kernel(
    const float* __restrict__ x, float* __restrict__ sx) {
  const int t = blockIdx.x * 256 + threadIdx.x;  // [0, B*HW)
  const int b = t >> 18;
  const int s = t & (HW - 1);
  const float* xp = x + (size_t)b * 19 * HW + s;
  float bv = *xp;
  float ix = 0.f;
#pragma unroll
  for (int c = 1; c < 19; ++c) {
    const float v = xp[(size_t)c * HW];
    if (v > bv) { bv = v; ix = (float)c; }
  }
  sx[(size_t)b * HW + s] = ix;
}

// ---------------------------------------------------------------------------
extern "C" void kernel_launch(void* const* d_in, const int* in_sizes, int n_in,
                              void* d_out, int out_size, void* d_ws,
                              size_t ws_size, hipStream_t stream) {
  const float* x     = (const float*)d_in[0];
  const float* image = (const float*)d_in[1];
  const float* iw1 = (const float*)d_in[2];
  const float* ib1 = (const float*)d_in[3];
  const float* iw2 = (const float*)d_in[4];
  const float* ib2 = (const float*)d_in[5];
  const float* iw3 = (const float*)d_in[6];
  const float* ib3 = (const float*)d_in[7];
  const float* gw1 = (const float*)d_in[8];
  const float* gb1 = (const float*)d_in[9];
  const float* gw2 = (const float*)d_in[10];
  const float* gb2 = (const float*)d_in[11];
  const float* gw3 = (const float*)d_in[12];
  const float* gb3 = (const float*)d_in[13];

  // Workspace layout in FLOAT units (1 float = 2 bf16):
  //   sx   [  0,   2)*HW   argmax map
  //   f1p  [  2,  18)*HW   [B][H][W][16] bf16
  //   intp [ 34,  58)*HW   [B][H][W][24] bf16
  //   g1p  [ 58,  90)*HW   [B][H][W][32] bf16
  //   bpacks at 122*HW
  float* ws = (float*)d_ws;
  float* sx = ws;
  unsigned short* f1p  = (unsigned short*)(ws + (size_t)2 * HW);
  unsigned short* intp = (unsigned short*)(ws + (size_t)34 * HW);
  unsigned short* g1p  = (unsigned short*)(ws + (size_t)58 * HW);
  unsigned short* bp_ic2 = (unsigned short*)(ws + (size_t)122 * HW);  // 2560
  unsigned short* bp_gc1 = bp_ic2 + 4096;                             // 7168
  unsigned short* bp_gc2 = bp_gc1 + 12288;                            // 9216

  float* out0 = (float*)d_out;               // (2,19,512,512)
  float* gfo  = out0 + (size_t)2 * 19 * HW;  // (2,11,1,512,512)
  float* edg  = gfo + (size_t)2 * 11 * HW;   // (2,1,512,512)

  const dim3 blk16(16, 16);
  const dim3 grd16(W / 16, H / 16, B);
  const dim3 grdM(W / 32, H / 8, B);     // 32x8 tiles -> 2048 blocks
  const int flat1 = (B * HW) / 256;      // 2048 blocks, 1 px/thread

  // 6 dispatches: argmax, repack_all, pack, conv16, conv24(+edge),
  // conv32(+1x1+combine).
  argmax_kernel<<<flat1, 256, 0, stream>>>(x, sx);
  repack_all<<<74, 256, 0, stream>>>(iw2, gw1, gw2, bp_ic2, bp_gc1, bp_gc2);

  conv3x3_fp32_pack<3, 16, true><<<grd16, blk16, 0, stream>>>(image, iw1, ib1, f1p);
  // intra conv2 (16->16) + fused 1x1 16->19 -> packed intra [H][W][24]
  conv3x3_mfma<16, 5, 1, false, 1><<<grdM, 256, 0, stream>>>(
      f1p, nullptr, bp_ic2, ib2, iw3, ib3, intp, nullptr, nullptr, nullptr, nullptr);
  // guide conv1 (20->32) + inline edge from sx; LDS-bounce vector stores
  conv3x3_mfma<24, 7, 2, true, 4><<<grdM, 256, 0, stream>>>(
      intp, sx, bp_gc1, gb1, nullptr, nullptr, g1p, edg, nullptr, nullptr, nullptr);
  // guide conv2 (32->32) + fused 1x1 32->11 + sigmoid + normalize -> gfo
  // + fused combine (pinned two-phase x-stage, tap-major xs) -> out0
  conv3x3_mfma<32, 9, 2, false, 3><<<grdM, 256, 0, stream>>>(
      g1p, nullptr, bp_gc2, gb2, gw3, gb3, nullptr, gfo, x, intp, out0);
}

// Round 12
// 221.777 us; speedup vs baseline: 1.0725x; 1.0725x over previous
//
#include <hip/hip_runtime.h>
#include <math.h>

// Problem constants (fixed by setup_inputs): B=2, C=19, H=W=512, fp32 in/out.
constexpr int H = 512, W = 512, B = 2;
constexpr int HW = H * W;

typedef __attribute__((ext_vector_type(8))) short short8;
typedef __attribute__((ext_vector_type(4))) float floatx4;
typedef __attribute__((ext_vector_type(4))) unsigned int uint4v;

__device__ inline unsigned short f2bf(float f) {
  union { float f; unsigned int u; } x{f};
  const unsigned int u = x.u;
  return (unsigned short)((u + 0x7FFFu + ((u >> 16) & 1u)) >> 16);
}
__device__ inline float bf2f(unsigned short s) {
  union { unsigned int u; float f; } x;
  x.u = (unsigned int)s << 16;
  return x.f;
}
// unpack packed bf16 pair (one dword) -> two floats
__device__ inline void unpk2(unsigned int u, float& lo, float& hi) {
  union { unsigned int u; float f; } a, b;
  a.u = u << 16;
  b.u = u & 0xffff0000u;
  lo = a.f;
  hi = b.f;
}

// 3-wide row load for 1-px stencils: r[1] = col w.
__device__ inline void load_row3(const float* __restrict__ plane, int hh,
                                 int w, float r[3]) {
  r[0] = 0.f; r[1] = 0.f; r[2] = 0.f;
  if ((unsigned)hh < (unsigned)H) {
    const float* rp = plane + (size_t)hh * W + w;
    r[1] = rp[0];
    if (w > 0) r[0] = rp[-1];
    if (w + 1 < W) r[2] = rp[1];
  }
}

// ---------------------------------------------------------------------------
// fp32 tiled 3x3 conv 3->16, writes bf16 NHWC packed output [B][H][W][16].
// ---------------------------------------------------------------------------
template <int CIN, int COUT, bool RELU>
__global__ __launch_bounds__(256) void conv3x3_fp32_pack(
    const float* __restrict__ in0, const float* __restrict__ wgt,
    const float* __restrict__ bias, unsigned short* __restrict__ outp) {
  constexpr int TS = 16, TH = 18, LDW = 20;
  __shared__ float tile[CIN][TH][LDW];
  const int tx = threadIdx.x, ty = threadIdx.y;
  const int tid = ty * 16 + tx;
  const int w0 = blockIdx.x * TS, h0 = blockIdx.y * TS, b = blockIdx.z;

  for (int idx = tid; idx < CIN * TH * TH; idx += 256) {
    const int cin = idx / (TH * TH);
    const int rem = idx - cin * (TH * TH);
    const int r = rem / TH, c = rem - r * TH;
    const int gh = h0 + r - 1, gw = w0 + c - 1;
    float v = 0.f;
    if ((unsigned)gh < (unsigned)H && (unsigned)gw < (unsigned)W)
      v = in0[(size_t)(b * CIN + cin) * HW + gh * W + gw];
    tile[cin][r][c] = v;
  }
  __syncthreads();

  float acc[COUT];
#pragma unroll
  for (int co = 0; co < COUT; ++co) acc[co] = bias[co];
  for (int cin = 0; cin < CIN; ++cin) {
#pragma unroll
    for (int t = 0; t < 9; ++t) {
      const int ky = t / 3, kx = t - ky * 3;
      const float v = tile[cin][ty + ky][tx + kx];
#pragma unroll
      for (int co = 0; co < COUT; ++co)
        acc[co] = fmaf(v, wgt[(co * CIN + cin) * 9 + t], acc[co]);
    }
  }
  const int oh = h0 + ty, ow = w0 + tx;
  unsigned int pk[COUT / 2];
#pragma unroll
  for (int c2 = 0; c2 < COUT / 2; ++c2) {
    float a0 = acc[2 * c2], a1 = acc[2 * c2 + 1];
    if (RELU) { a0 = fmaxf(a0, 0.f); a1 = fmaxf(a1, 0.f); }
    pk[c2] = (unsigned)f2bf(a0) | ((unsigned)f2bf(a1) << 16);
  }
  unsigned short* dst = outp + ((size_t)(b * H + oh) * W + ow) * COUT;
#pragma unroll
  for (int u = 0; u < COUT / 8; ++u)
    *(uint4v*)(dst + u * 8) = uint4v{pk[u * 4], pk[u * 4 + 1], pk[u * 4 + 2], pk[u * 4 + 3]};
}

// ---------------------------------------------------------------------------
// Weight repack into B-fragment order for mfma_f32_16x16x32_bf16.
// k = tap*CINP + cin (CINP mult of 8 so 8-runs stay within one tap).
// 3 launches merged into one kernel (round-7, ~3 us/dispatch boundary).
// ---------------------------------------------------------------------------
template <int CIN, int CINP, int COUT, int KS>
__device__ inline void repack_body(int idx, const float* __restrict__ w,
                                   unsigned short* __restrict__ bp) {
  constexpr int NT = COUT / 16;
  if (idx >= NT * KS * 512) return;
  const int j = idx & 7;
  const int l = (idx >> 3) & 63;
  const int ks = (idx >> 9) % KS;
  const int nt = idx / (KS * 512);
  const int co = nt * 16 + (l & 15);
  const int kglob = ks * 32 + (l >> 4) * 8 + j;
  const int tap = kglob / CINP;
  const int cin = kglob % CINP;
  float v = 0.f;
  if (tap < 9 && cin < CIN) v = w[((size_t)co * CIN + cin) * 9 + tap];
  bp[idx] = f2bf(v);
}

__global__ __launch_bounds__(256) void repack_all(
    const float* __restrict__ iw2, const float* __restrict__ gw1,
    const float* __restrict__ gw2, unsigned short* __restrict__ bp_ic2,
    unsigned short* __restrict__ bp_gc1, unsigned short* __restrict__ bp_gc2) {
  const int blk = blockIdx.x, tid = threadIdx.x;
  if (blk < 10) {
    repack_body<16, 16, 16, 5>(blk * 256 + tid, iw2, bp_ic2);
  } else if (blk < 38) {
    repack_body<20, 24, 32, 7>((blk - 10) * 256 + tid, gw1, bp_gc1);
  } else {
    repack_body<32, 32, 32, 9>((blk - 38) * 256 + tid, gw2, bp_gc2);
  }
}

// ---------------------------------------------------------------------------
// Implicit-GEMM 3x3 conv via bf16 MFMA. Packed bf16 NHWC input [H][W][CINP].
// Round-12: tile = 32x4 px, 4 waves x 1 row; grid 4096 blocks; TR=6 halo
// rows; LDS 16.3 KB (CS=40) / 9.8 KB (CS=24). Rationale: the 32x8 fused
// kernel's realized occupancy (27-36%) sat far under its 5-block LDS cap
// because each block is a long serial chain (stage -> MFMA -> 1x1 ->
// x-stage -> combine); more, shorter blocks interleave these phases across
// blocks (same lever as round-3's 57->\<51 us win). Round-11's pinned
// register prefetch is REVERTED (VGPR 92 collapsed occupancy to 19%,
// -5 us); conv24 reverted to EPI=0 direct stores (EPI=4 bounce regressed).
// EPI=0: packed bf16 NHWC output (bias+relu, direct scalar stores).
// EPI=1: fused 1x1 16->19 (intra head) -> packed [H][W][24] (ch19..23=0).
// EPI=3: fused 1x1 32->11 + sigmoid + normalize -> gfo, + fused combine via
//        serial LDS-staged x window (round-8 form, known-good).
// EDGE19: edg = argmax map sx; inline 3x3 Laplacian during staging, written
//        to LDS ch19 and the edge output plane (halo rewrites benign).
// ---------------------------------------------------------------------------
template <int CINP, int KS, int NT, bool EDGE19, int EPI>
__global__ __launch_bounds__(256) void conv3x3_mfma(
    const unsigned short* __restrict__ inp, const float* __restrict__ edg,
    const unsigned short* __restrict__ bpack, const float* __restrict__ bias,
    const float* __restrict__ ew, const float* __restrict__ eb,
    unsigned short* __restrict__ outp, float* __restrict__ outf,
    const float* __restrict__ xin, const unsigned short* __restrict__ ipn,
    float* __restrict__ outc) {
  constexpr int COUT = NT * 16;
  constexpr int CS = (CINP == 16) ? 24 : 40;  // LDS cin stride (16B mult)
  constexpr int EPS = (EPI == 1) ? 24 : 40;   // epilogue LDS px stride
  constexpr int TROWS = 4;                    // output rows per tile
  constexpr int TR = TROWS + 2;               // + halo
  constexpr int NPX = TROWS * 32;             // 128 px per tile
  constexpr int XN = 19 * TR * 34;            // x stencil window elems (3876)
  __shared__ __align__(16) unsigned short tile[TR * 34 * CS];

  const int tid = threadIdx.x;
  const int w0 = blockIdx.x * 32, h0 = blockIdx.y * TROWS, b = blockIdx.z;

  // ---- stage halo'd tile: packed pixel copy (dwordx4), zero for OOB ----
  for (int idx = tid; idx < TR * 34; idx += 256) {
    const int r = idx / 34, c = idx - r * 34;
    const int gh = h0 + r - 1, gw = w0 + c - 1;
    unsigned short* dst = tile + (size_t)(r * 34 + c) * CS;
    if ((unsigned)gh < (unsigned)H && (unsigned)gw < (unsigned)W) {
      const unsigned short* src = inp + ((size_t)(b * H + gh) * W + gw) * CINP;
#pragma unroll
      for (int u = 0; u < CINP / 8; ++u)
        *(uint4v*)(dst + u * 8) = *(const uint4v*)(src + u * 8);
      if (EDGE19) {
        // inline Laplacian of the argmax map (exact integer fp32 sums)
        const float* sp = edg + (size_t)b * HW;
        float r0[3], r1[3], r2[3];
        load_row3(sp, gh - 1, gw, r0);
        load_row3(sp, gh, gw, r1);
        load_row3(sp, gh + 1, gw, r2);
        const float e = r0[0] + r0[1] + r0[2] + r1[0] + r1[2] + r2[0] +
                        r2[1] + r2[2] - 8.f * r1[1];
        dst[19] = f2bf(e);
        outf[(size_t)b * HW + (size_t)gh * W + gw] = e;
      }
    } else {
#pragma unroll
      for (int u = 0; u < CINP / 8; ++u)
        *(uint4v*)(dst + u * 8) = uint4v{0, 0, 0, 0};
    }
  }
  __syncthreads();

  // ---- K-loop (fully unrolled); 1 output row per wave ----
  const int wv = tid >> 6, lane = tid & 63;
  const int q = lane >> 4, l15 = lane & 15;
  const int rb = wv;  // wave's output row within tile

  floatx4 acc[2][NT];
#pragma unroll
  for (int mf = 0; mf < 2; ++mf)
#pragma unroll
    for (int nt = 0; nt < NT; ++nt) acc[mf][nt] = floatx4{0.f, 0.f, 0.f, 0.f};

#pragma unroll
  for (int ks = 0; ks < KS; ++ks) {
    short8 bfrag[NT];
#pragma unroll
    for (int nt = 0; nt < NT; ++nt)
      bfrag[nt] = *(const short8*)(bpack + (size_t)(((nt * KS) + ks) * 64 + lane) * 8);

    const int kbase = ks * 32;  // compile-time
    const int kq = kbase + q * 8;
    int tapq = kq / CINP;
    const int cinq = kq % CINP;
    if (tapq > 8) tapq = 8;  // zero-weight pad region
    const int ky = tapq / 3, kx = tapq - ky * 3;
    const unsigned short* aptr =
        tile + (size_t)((rb + ky) * 34 + (l15 + kx)) * CS + cinq;

#pragma unroll
    for (int mf = 0; mf < 2; ++mf) {
      const int off = (mf & 1) * 16 * CS;
      const short8 af = *(const short8*)(aptr + off);
#pragma unroll
      for (int nt = 0; nt < NT; ++nt)
        acc[mf][nt] = __builtin_amdgcn_mfma_f32_16x16x32_bf16(
            af, bfrag[nt], acc[mf][nt], 0, 0, 0);
    }
  }

  if constexpr (EPI == 0) {
    // ---- direct bf16 short stores from C-layout registers ----
    // D layout: n (=co within tile) = l15, m (=pixel col) = q*4 + rg.
#pragma unroll
    for (int nt = 0; nt < NT; ++nt) {
      const float bv = bias[nt * 16 + l15];
#pragma unroll
      for (int mf = 0; mf < 2; ++mf) {
        const int colb = (mf & 1) * 16 + q * 4;
        unsigned short* dst =
            outp + ((size_t)(b * H + h0 + rb) * W + w0) * COUT + nt * 16 + l15;
#pragma unroll
        for (int rg = 0; rg < 4; ++rg) {
          const float v = fmaxf(acc[mf][nt][rg] + bv, 0.f);
          dst[(size_t)(colb + rg) * COUT] = f2bf(v);
        }
      }
    }
  } else {
    // ---- fused epilogue: conv out (bias+relu, bf16) -> LDS bounce ----
    __syncthreads();  // all waves done reading the staging tile
#pragma unroll
    for (int nt = 0; nt < NT; ++nt) {
      const float bv = bias[nt * 16 + l15];
#pragma unroll
      for (int mf = 0; mf < 2; ++mf) {
        const int colb = (mf & 1) * 16 + q * 4;
#pragma unroll
        for (int rg = 0; rg < 4; ++rg) {
          const int px = rb * 32 + colb + rg;
          tile[(size_t)px * EPS + nt * 16 + l15] =
              f2bf(fmaxf(acc[mf][nt][rg] + bv, 0.f));
        }
      }
    }
    __syncthreads();

    {
      const int p = tid;                       // NPX px per tile
      const bool act = p < NPX;
      const int gh = h0 + (p >> 5), gw = w0 + (p & 31);
      const unsigned short* src = tile + (size_t)p * EPS;

      if constexpr (EPI == 1) {
        if (act) {
          // 1x1 conv 16->19 (no relu), pack to [H][W][24] (ch19..23 = 0)
          float xi[16];
          const uint4v r0 = *(const uint4v*)src;
          const uint4v r1 = *(const uint4v*)(src + 8);
          unpk2(r0.x, xi[0], xi[1]);   unpk2(r0.y, xi[2], xi[3]);
          unpk2(r0.z, xi[4], xi[5]);   unpk2(r0.w, xi[6], xi[7]);
          unpk2(r1.x, xi[8], xi[9]);   unpk2(r1.y, xi[10], xi[11]);
          unpk2(r1.z, xi[12], xi[13]); unpk2(r1.w, xi[14], xi[15]);
          float a[19];
#pragma unroll
          for (int co = 0; co < 19; ++co) a[co] = eb[co];
#pragma unroll
          for (int c = 0; c < 16; ++c) {
            const float v = xi[c];
#pragma unroll
            for (int co = 0; co < 19; ++co) a[co] = fmaf(v, ew[co * 16 + c], a[co]);
          }
          unsigned int pk[12];
#pragma unroll
          for (int j = 0; j < 9; ++j)
            pk[j] = (unsigned)f2bf(a[2 * j]) | ((unsigned)f2bf(a[2 * j + 1]) << 16);
          pk[9] = (unsigned)f2bf(a[18]);
          pk[10] = 0; pk[11] = 0;
          unsigned short* dst = outp + ((size_t)(b * H + gh) * W + gw) * 24;
#pragma unroll
          for (int u = 0; u < 3; ++u)
            *(uint4v*)(dst + u * 8) =
                uint4v{pk[u * 4], pk[u * 4 + 1], pk[u * 4 + 2], pk[u * 4 + 3]};
        }
      } else {
        // EPI==3: 1x1 conv 32->11 + sigmoid + normalize + fused combine
        float xi[32];
        if (act) {
#pragma unroll
          for (int u = 0; u < 4; ++u) {
            const uint4v r = *(const uint4v*)(src + u * 8);
            unpk2(r.x, xi[u * 8 + 0], xi[u * 8 + 1]);
            unpk2(r.y, xi[u * 8 + 2], xi[u * 8 + 3]);
            unpk2(r.z, xi[u * 8 + 4], xi[u * 8 + 5]);
            unpk2(r.w, xi[u * 8 + 6], xi[u * 8 + 7]);
          }
        }
        __syncthreads();  // conv-out read; tile now dead

        float g[11], sum = 0.f;
        float inv = 0.f;
        size_t s = 0;
        if (act) {
#pragma unroll
          for (int co = 0; co < 11; ++co) {
            float a = eb[co];
#pragma unroll
            for (int c = 0; c < 32; ++c) a = fmaf(xi[c], ew[co * 32 + c], a);
            g[co] = 1.f / (1.f + expf(-a));
            sum += g[co];
          }
          inv = 1.f / (sum + 1e-9f);
          s = (size_t)gh * W + gw;
#pragma unroll
          for (int co = 0; co < 11; ++co)
            outf[(size_t)(b * 11 + co) * HW + s] = g[co] * inv;
        }

        // ---- stage x stencil window into LDS (exact copies), all threads --
        // xs[c][r][col] : 19 x TR x 34 fp32 = 15504 B (tile = 16320 B)
        float* xs = (float*)tile;
        for (int idx = tid; idx < XN; idx += 256) {
          const int c = idx / (TR * 34);
          const int rem = idx - c * (TR * 34);
          const int r = rem / 34, col = rem - r * 34;
          const int gh2 = h0 + r - 1, gw2 = w0 + col - 1;
          float v = 0.f;
          if ((unsigned)gh2 < (unsigned)H && (unsigned)gw2 < (unsigned)W)
            v = xin[(size_t)(b * 19 + c) * HW + (size_t)gh2 * W + gw2];
          xs[idx] = v;
        }
        __syncthreads();

        if (act) {
          // fused combine for this pixel: gn[m] = g[m]*inv is bit-identical
          // to the fp32 store/load of gfo the standalone kernel did.
          float gn[11];
#pragma unroll
          for (int m = 0; m < 11; ++m) gn[m] = g[m] * inv;
          const int pr = p >> 5, pc = p & 31;
          const unsigned short* ip = ipn + ((size_t)b * HW + s) * 24;
          for (int c = 0; c < 19; ++c) {
            const float* xc = xs + c * (TR * 34);
            const float* x0 = xc + (pr + 0) * 34 + pc;  // row gh-1
            const float* x1 = xc + (pr + 1) * 34 + pc;  // row gh
            const float* x2 = xc + (pr + 2) * 34 + pc;  // row gh+1
            const float itv = bf2f(ip[c]);
            float a = gn[0] * x1[1];
            a = fmaf(gn[1], x0[0], a);
            a = fmaf(gn[2], x0[1], a);
            a = fmaf(gn[3], x0[2], a);
            a = fmaf(gn[4], x1[0], a);
            a = fmaf(gn[5], x1[2], a);
            a = fmaf(gn[6], x2[0], a);
            a = fmaf(gn[7], x2[1], a);
            a = fmaf(gn[8], x2[2], a);
            a = fmaf(gn[10], itv, a);
            outc[(size_t)(b * 19 + c) * HW + s] = a;
          }
        }
      }
    }
  }
}

// ---------------------------------------------------------------------------
// argmax over 19 channels -> float index, 1 pixel/thread.
// ---------------------------------------------------------------------------
__global__ __launch_bounds__(256) void argmax_kernel(
    const float* __restrict__ x, float* __restrict__ sx) {
  const int t = blockIdx.x * 256 + threadIdx.x;  // [0, B*HW)
  const int b = t >> 18;
  const int s = t & (HW - 1);
  const float* xp = x + (size_t)b * 19 * HW + s;
  float bv = *xp;
  float ix = 0.f;
#pragma unroll
  for (int c = 1; c < 19; ++c) {
    const float v = xp[(size_t)c * HW];
    if (v > bv) { bv = v; ix = (float)c; }
  }
  sx[(size_t)b * HW + s] = ix;
}

// ---------------------------------------------------------------------------
extern "C" void kernel_launch(void* const* d_in, const int* in_sizes, int n_in,
                              void* d_out, int out_size, void* d_ws,
                              size_t ws_size, hipStream_t stream) {
  const float* x     = (const float*)d_in[0];
  const float* image = (const float*)d_in[1];
  const float* iw1 = (const float*)d_in[2];
  const float* ib1 = (const float*)d_in[3];
  const float* iw2 = (const float*)d_in[4];
  const float* ib2 = (const float*)d_in[5];
  const float* iw3 = (const float*)d_in[6];
  const float* ib3 = (const float*)d_in[7];
  const float* gw1 = (const float*)d_in[8];
  const float* gb1 = (const float*)d_in[9];
  const float* gw2 = (const float*)d_in[10];
  const float* gb2 = (const float*)d_in[11];
  const float* gw3 = (const float*)d_in[12];
  const float* gb3 = (const float*)d_in[13];

  // Workspace layout in FLOAT units (1 float = 2 bf16):
  //   sx   [  0,   2)*HW   argmax map
  //   f1p  [  2,  18)*HW   [B][H][W][16] bf16
  //   intp [ 34,  58)*HW   [B][H][W][24] bf16
  //   g1p  [ 58,  90)*HW   [B][H][W][32] bf16
  //   bpacks at 122*HW
  float* ws = (float*)d_ws;
  float* sx = ws;
  unsigned short* f1p  = (unsigned short*)(ws + (size_t)2 * HW);
  unsigned short* intp = (unsigned short*)(ws + (size_t)34 * HW);
  unsigned short* g1p  = (unsigned short*)(ws + (size_t)58 * HW);
  unsigned short* bp_ic2 = (unsigned short*)(ws + (size_t)122 * HW);  // 2560
  unsigned short* bp_gc1 = bp_ic2 + 4096;                             // 7168
  unsigned short* bp_gc2 = bp_gc1 + 12288;                            // 9216

  float* out0 = (float*)d_out;               // (2,19,512,512)
  float* gfo  = out0 + (size_t)2 * 19 * HW;  // (2,11,1,512,512)
  float* edg  = gfo + (size_t)2 * 11 * HW;   // (2,1,512,512)

  const dim3 blk16(16, 16);
  const dim3 grd16(W / 16, H / 16, B);
  const dim3 grdM(W / 32, H / 4, B);     // 32x4 tiles -> 4096 blocks
  const int flat1 = (B * HW) / 256;      // 2048 blocks, 1 px/thread

  // 6 dispatches: argmax, repack_all, pack, conv16, conv24(+edge),
  // conv32(+1x1+combine).
  argmax_kernel<<<flat1, 256, 0, stream>>>(x, sx);
  repack_all<<<74, 256, 0, stream>>>(iw2, gw1, gw2, bp_ic2, bp_gc1, bp_gc2);

  conv3x3_fp32_pack<3, 16, true><<<grd16, blk16, 0, stream>>>(image, iw1, ib1, f1p);
  // intra conv2 (16->16) + fused 1x1 16->19 -> packed intra [H][W][24]
  conv3x3_mfma<16, 5, 1, false, 1><<<grdM, 256, 0, stream>>>(
      f1p, nullptr, bp_ic2, ib2, iw3, ib3, intp, nullptr, nullptr, nullptr, nullptr);
  // guide conv1 (20->32) + inline edge from sx (writes edg output) -> g1p
  conv3x3_mfma<24, 7, 2, true, 0><<<grdM, 256, 0, stream>>>(
      intp, sx, bp_gc1, gb1, nullptr, nullptr, g1p, edg, nullptr, nullptr, nullptr);
  // guide conv2 (32->32) + fused 1x1 32->11 + sigmoid + normalize -> gfo
  // + fused combine (serial LDS-staged x window, round-8 form) -> out0
  conv3x3_mfma<32, 9, 2, false, 3><<<grdM, 256, 0, stream>>>(
      g1p, nullptr, bp_gc2, gb2, gw3, gb3, nullptr, gfo, x, intp, out0);
}

// Round 13
// 218.871 us; speedup vs baseline: 1.0867x; 1.0133x over previous
//
#include <hip/hip_runtime.h>
#include <math.h>

// Problem constants (fixed by setup_inputs): B=2, C=19, H=W=512, fp32 in/out.
constexpr int H = 512, W = 512, B = 2;
constexpr int HW = H * W;

typedef __attribute__((ext_vector_type(8))) short short8;
typedef __attribute__((ext_vector_type(4))) float floatx4;
typedef __attribute__((ext_vector_type(4))) unsigned int uint4v;

__device__ inline unsigned short f2bf(float f) {
  union { float f; unsigned int u; } x{f};
  const unsigned int u = x.u;
  return (unsigned short)((u + 0x7FFFu + ((u >> 16) & 1u)) >> 16);
}
__device__ inline float bf2f(unsigned short s) {
  union { unsigned int u; float f; } x;
  x.u = (unsigned int)s << 16;
  return x.f;
}
// unpack packed bf16 pair (one dword) -> two floats
__device__ inline void unpk2(unsigned int u, float& lo, float& hi) {
  union { unsigned int u; float f; } a, b;
  a.u = u << 16;
  b.u = u & 0xffff0000u;
  lo = a.f;
  hi = b.f;
}

// 3-wide row load for 1-px stencils: r[1] = col w.
__device__ inline void load_row3(const float* __restrict__ plane, int hh,
                                 int w, float r[3]) {
  r[0] = 0.f; r[1] = 0.f; r[2] = 0.f;
  if ((unsigned)hh < (unsigned)H) {
    const float* rp = plane + (size_t)hh * W + w;
    r[1] = rp[0];
    if (w > 0) r[0] = rp[-1];
    if (w + 1 < W) r[2] = rp[1];
  }
}

// ---------------------------------------------------------------------------
// Weight repack into B-fragment order for mfma_f32_16x16x32_bf16.
// k = tap*CINP + cin (CINP mult of 8 so 8-runs stay within one tap).
// ---------------------------------------------------------------------------
template <int CIN, int CINP, int COUT, int KS>
__device__ inline void repack_body(int idx, const float* __restrict__ w,
                                   unsigned short* __restrict__ bp) {
  constexpr int NT = COUT / 16;
  if (idx >= NT * KS * 512) return;
  const int j = idx & 7;
  const int l = (idx >> 3) & 63;
  const int ks = (idx >> 9) % KS;
  const int nt = idx / (KS * 512);
  const int co = nt * 16 + (l & 15);
  const int kglob = ks * 32 + (l >> 4) * 8 + j;
  const int tap = kglob / CINP;
  const int cin = kglob % CINP;
  float v = 0.f;
  if (tap < 9 && cin < CIN) v = w[((size_t)co * CIN + cin) * 9 + tap];
  bp[idx] = f2bf(v);
}

// ---------------------------------------------------------------------------
// Prelude mega-kernel (round-13): argmax (2048 blocks) + fp32 3x3 conv 3->16
// pack (2048 blocks) + weight repacks (74 blocks) have NO mutual deps --
// merged into one dispatch. Kills 2 launch boundaries (~3 us each measured
// round-7) and co-schedules the latency-bound argmax reader with the
// VALU-bound pack producer. Branch on blockIdx.x is block-uniform, so the
// pack branch's barriers are safe. Per-thread code paths identical to the
// previous standalone kernels -> bit-identical outputs.
// ---------------------------------------------------------------------------
__global__ __launch_bounds__(256) void prelude_kernel(
    const float* __restrict__ x, float* __restrict__ sx,
    const float* __restrict__ image, const float* __restrict__ iw1,
    const float* __restrict__ ib1, unsigned short* __restrict__ f1p,
    const float* __restrict__ iw2, const float* __restrict__ gw1,
    const float* __restrict__ gw2, unsigned short* __restrict__ bp_ic2,
    unsigned short* __restrict__ bp_gc1, unsigned short* __restrict__ bp_gc2) {
  const int blk = blockIdx.x, tid = threadIdx.x;

  if (blk < 2048) {
    // ---- argmax over 19 channels -> float index, 1 pixel/thread ----
    const int t = blk * 256 + tid;  // [0, B*HW)
    const int b = t >> 18;
    const int s = t & (HW - 1);
    const float* xp = x + (size_t)b * 19 * HW + s;
    float bv = *xp;
    float ix = 0.f;
#pragma unroll
    for (int c = 1; c < 19; ++c) {
      const float v = xp[(size_t)c * HW];
      if (v > bv) { bv = v; ix = (float)c; }
    }
    sx[(size_t)b * HW + s] = ix;
  } else if (blk < 4096) {
    // ---- fp32 tiled 3x3 conv 3->16 -> bf16 NHWC [B][H][W][16] ----
    constexpr int CIN = 3, COUT = 16, TS = 16, TH = 18, LDW = 20;
    __shared__ float tile[CIN][TH][LDW];
    const int pid = blk - 2048;          // grid was (32, 32, B)
    const int b = pid >> 10;
    const int rem = pid & 1023;
    const int by = rem >> 5, bx = rem & 31;
    const int w0 = bx * TS, h0 = by * TS;
    const int tx = tid & 15, ty = tid >> 4;

    for (int idx = tid; idx < CIN * TH * TH; idx += 256) {
      const int cin = idx / (TH * TH);
      const int r2 = idx - cin * (TH * TH);
      const int r = r2 / TH, c = r2 - r * TH;
      const int gh = h0 + r - 1, gw = w0 + c - 1;
      float v = 0.f;
      if ((unsigned)gh < (unsigned)H && (unsigned)gw < (unsigned)W)
        v = image[(size_t)(b * CIN + cin) * HW + gh * W + gw];
      tile[cin][r][c] = v;
    }
    __syncthreads();

    float acc[COUT];
#pragma unroll
    for (int co = 0; co < COUT; ++co) acc[co] = ib1[co];
    for (int cin = 0; cin < CIN; ++cin) {
#pragma unroll
      for (int t = 0; t < 9; ++t) {
        const int ky = t / 3, kx = t - ky * 3;
        const float v = tile[cin][ty + ky][tx + kx];
#pragma unroll
        for (int co = 0; co < COUT; ++co)
          acc[co] = fmaf(v, iw1[(co * CIN + cin) * 9 + t], acc[co]);
      }
    }
    const int oh = h0 + ty, ow = w0 + tx;
    unsigned int pk[COUT / 2];
#pragma unroll
    for (int c2 = 0; c2 < COUT / 2; ++c2) {
      float a0 = fmaxf(acc[2 * c2], 0.f), a1 = fmaxf(acc[2 * c2 + 1], 0.f);
      pk[c2] = (unsigned)f2bf(a0) | ((unsigned)f2bf(a1) << 16);
    }
    unsigned short* dst = f1p + ((size_t)(b * H + oh) * W + ow) * COUT;
#pragma unroll
    for (int u = 0; u < COUT / 8; ++u)
      *(uint4v*)(dst + u * 8) =
          uint4v{pk[u * 4], pk[u * 4 + 1], pk[u * 4 + 2], pk[u * 4 + 3]};
  } else {
    // ---- weight repacks ----
    const int rblk = blk - 4096;
    if (rblk < 10) {
      repack_body<16, 16, 16, 5>(rblk * 256 + tid, iw2, bp_ic2);
    } else if (rblk < 38) {
      repack_body<20, 24, 32, 7>((rblk - 10) * 256 + tid, gw1, bp_gc1);
    } else {
      repack_body<32, 32, 32, 9>((rblk - 38) * 256 + tid, gw2, bp_gc2);
    }
  }
}

// ---------------------------------------------------------------------------
// Implicit-GEMM 3x3 conv via bf16 MFMA. Packed bf16 NHWC input [H][W][CINP].
// Tile = 32x4 px, 4 waves x 1 row; grid 4096 blocks; TR=6 halo rows; LDS
// 16.3 KB (CS=40) / 9.8 KB (CS=24). Round-12 confirmed: occupancy 27->49%,
// VGPR 40. Round-11's pinned register prefetch REVERTED (VGPR 92 collapsed
// occupancy); conv24 keeps EPI=0 direct stores (EPI=4 bounce regressed).
// EPI=0: packed bf16 NHWC output (bias+relu, direct scalar stores).
// EPI=1: fused 1x1 16->19 (intra head) -> packed [H][W][24] (ch19..23=0).
// EPI=3: fused 1x1 32->11 + sigmoid + normalize -> gfo, + fused combine via
//        serial LDS-staged x window (round-8 form, known-good).
// EDGE19: edg = argmax map sx; inline 3x3 Laplacian during staging, written
//        to LDS ch19 and the edge output plane (halo rewrites benign).
// ---------------------------------------------------------------------------
template <int CINP, int KS, int NT, bool EDGE19, int EPI>
__global__ __launch_bounds__(256) void conv3x3_mfma(
    const unsigned short* __restrict__ inp, const float* __restrict__ edg,
    const unsigned short* __restrict__ bpack, const float* __restrict__ bias,
    const float* __restrict__ ew, const float* __restrict__ eb,
    unsigned short* __restrict__ outp, float* __restrict__ outf,
    const float* __restrict__ xin, const unsigned short* __restrict__ ipn,
    float* __restrict__ outc) {
  constexpr int COUT = NT * 16;
  constexpr int CS = (CINP == 16) ? 24 : 40;  // LDS cin stride (16B mult)
  constexpr int EPS = (EPI == 1) ? 24 : 40;   // epilogue LDS px stride
  constexpr int TROWS = 4;                    // output rows per tile
  constexpr int TR = TROWS + 2;               // + halo
  constexpr int NPX = TROWS * 32;             // 128 px per tile
  constexpr int XN = 19 * TR * 34;            // x stencil window elems (3876)
  __shared__ __align__(16) unsigned short tile[TR * 34 * CS];

  const int tid = threadIdx.x;
  const int w0 = blockIdx.x * 32, h0 = blockIdx.y * TROWS, b = blockIdx.z;

  // ---- stage halo'd tile: packed pixel copy (dwordx4), zero for OOB ----
  for (int idx = tid; idx < TR * 34; idx += 256) {
    const int r = idx / 34, c = idx - r * 34;
    const int gh = h0 + r - 1, gw = w0 + c - 1;
    unsigned short* dst = tile + (size_t)(r * 34 + c) * CS;
    if ((unsigned)gh < (unsigned)H && (unsigned)gw < (unsigned)W) {
      const unsigned short* src = inp + ((size_t)(b * H + gh) * W + gw) * CINP;
#pragma unroll
      for (int u = 0; u < CINP / 8; ++u)
        *(uint4v*)(dst + u * 8) = *(const uint4v*)(src + u * 8);
      if (EDGE19) {
        // inline Laplacian of the argmax map (exact integer fp32 sums)
        const float* sp = edg + (size_t)b * HW;
        float r0[3], r1[3], r2[3];
        load_row3(sp, gh - 1, gw, r0);
        load_row3(sp, gh, gw, r1);
        load_row3(sp, gh + 1, gw, r2);
        const float e = r0[0] + r0[1] + r0[2] + r1[0] + r1[2] + r2[0] +
                        r2[1] + r2[2] - 8.f * r1[1];
        dst[19] = f2bf(e);
        outf[(size_t)b * HW + (size_t)gh * W + gw] = e;
      }
    } else {
#pragma unroll
      for (int u = 0; u < CINP / 8; ++u)
        *(uint4v*)(dst + u * 8) = uint4v{0, 0, 0, 0};
    }
  }
  __syncthreads();

  // ---- K-loop (fully unrolled); 1 output row per wave ----
  const int wv = tid >> 6, lane = tid & 63;
  const int q = lane >> 4, l15 = lane & 15;
  const int rb = wv;  // wave's output row within tile

  floatx4 acc[2][NT];
#pragma unroll
  for (int mf = 0; mf < 2; ++mf)
#pragma unroll
    for (int nt = 0; nt < NT; ++nt) acc[mf][nt] = floatx4{0.f, 0.f, 0.f, 0.f};

#pragma unroll
  for (int ks = 0; ks < KS; ++ks) {
    short8 bfrag[NT];
#pragma unroll
    for (int nt = 0; nt < NT; ++nt)
      bfrag[nt] = *(const short8*)(bpack + (size_t)(((nt * KS) + ks) * 64 + lane) * 8);

    const int kbase = ks * 32;  // compile-time
    const int kq = kbase + q * 8;
    int tapq = kq / CINP;
    const int cinq = kq % CINP;
    if (tapq > 8) tapq = 8;  // zero-weight pad region
    const int ky = tapq / 3, kx = tapq - ky * 3;
    const unsigned short* aptr =
        tile + (size_t)((rb + ky) * 34 + (l15 + kx)) * CS + cinq;

#pragma unroll
    for (int mf = 0; mf < 2; ++mf) {
      const int off = (mf & 1) * 16 * CS;
      const short8 af = *(const short8*)(aptr + off);
#pragma unroll
      for (int nt = 0; nt < NT; ++nt)
        acc[mf][nt] = __builtin_amdgcn_mfma_f32_16x16x32_bf16(
            af, bfrag[nt], acc[mf][nt], 0, 0, 0);
    }
  }

  if constexpr (EPI == 0) {
    // ---- direct bf16 short stores from C-layout registers ----
    // D layout: n (=co within tile) = l15, m (=pixel col) = q*4 + rg.
#pragma unroll
    for (int nt = 0; nt < NT; ++nt) {
      const float bv = bias[nt * 16 + l15];
#pragma unroll
      for (int mf = 0; mf < 2; ++mf) {
        const int colb = (mf & 1) * 16 + q * 4;
        unsigned short* dst =
            outp + ((size_t)(b * H + h0 + rb) * W + w0) * COUT + nt * 16 + l15;
#pragma unroll
        for (int rg = 0; rg < 4; ++rg) {
          const float v = fmaxf(acc[mf][nt][rg] + bv, 0.f);
          dst[(size_t)(colb + rg) * COUT] = f2bf(v);
        }
      }
    }
  } else {
    // ---- fused epilogue: conv out (bias+relu, bf16) -> LDS bounce ----
    __syncthreads();  // all waves done reading the staging tile
#pragma unroll
    for (int nt = 0; nt < NT; ++nt) {
      const float bv = bias[nt * 16 + l15];
#pragma unroll
      for (int mf = 0; mf < 2; ++mf) {
        const int colb = (mf & 1) * 16 + q * 4;
#pragma unroll
        for (int rg = 0; rg < 4; ++rg) {
          const int px = rb * 32 + colb + rg;
          tile[(size_t)px * EPS + nt * 16 + l15] =
              f2bf(fmaxf(acc[mf][nt][rg] + bv, 0.f));
        }
      }
    }
    __syncthreads();

    {
      const int p = tid;                       // NPX px per tile
      const bool act = p < NPX;
      const int gh = h0 + (p >> 5), gw = w0 + (p & 31);
      const unsigned short* src = tile + (size_t)p * EPS;

      if constexpr (EPI == 1) {
        if (act) {
          // 1x1 conv 16->19 (no relu), pack to [H][W][24] (ch19..23 = 0)
          float xi[16];
          const uint4v r0 = *(const uint4v*)src;
          const uint4v r1 = *(const uint4v*)(src + 8);
          unpk2(r0.x, xi[0], xi[1]);   unpk2(r0.y, xi[2], xi[3]);
          unpk2(r0.z, xi[4], xi[5]);   unpk2(r0.w, xi[6], xi[7]);
          unpk2(r1.x, xi[8], xi[9]);   unpk2(r1.y, xi[10], xi[11]);
          unpk2(r1.z, xi[12], xi[13]); unpk2(r1.w, xi[14], xi[15]);
          float a[19];
#pragma unroll
          for (int co = 0; co < 19; ++co) a[co] = eb[co];
#pragma unroll
          for (int c = 0; c < 16; ++c) {
            const float v = xi[c];
#pragma unroll
            for (int co = 0; co < 19; ++co) a[co] = fmaf(v, ew[co * 16 + c], a[co]);
          }
          unsigned int pk[12];
#pragma unroll
          for (int j = 0; j < 9; ++j)
            pk[j] = (unsigned)f2bf(a[2 * j]) | ((unsigned)f2bf(a[2 * j + 1]) << 16);
          pk[9] = (unsigned)f2bf(a[18]);
          pk[10] = 0; pk[11] = 0;
          unsigned short* dst = outp + ((size_t)(b * H + gh) * W + gw) * 24;
#pragma unroll
          for (int u = 0; u < 3; ++u)
            *(uint4v*)(dst + u * 8) =
                uint4v{pk[u * 4], pk[u * 4 + 1], pk[u * 4 + 2], pk[u * 4 + 3]};
        }
      } else {
        // EPI==3: 1x1 conv 32->11 + sigmoid + normalize + fused combine
        float xi[32];
        if (act) {
#pragma unroll
          for (int u = 0; u < 4; ++u) {
            const uint4v r = *(const uint4v*)(src + u * 8);
            unpk2(r.x, xi[u * 8 + 0], xi[u * 8 + 1]);
            unpk2(r.y, xi[u * 8 + 2], xi[u * 8 + 3]);
            unpk2(r.z, xi[u * 8 + 4], xi[u * 8 + 5]);
            unpk2(r.w, xi[u * 8 + 6], xi[u * 8 + 7]);
          }
        }
        __syncthreads();  // conv-out read; tile now dead

        float g[11], sum = 0.f;
        float inv = 0.f;
        size_t s = 0;
        if (act) {
#pragma unroll
          for (int co = 0; co < 11; ++co) {
            float a = eb[co];
#pragma unroll
            for (int c = 0; c < 32; ++c) a = fmaf(xi[c], ew[co * 32 + c], a);
            g[co] = 1.f / (1.f + expf(-a));
            sum += g[co];
          }
          inv = 1.f / (sum + 1e-9f);
          s = (size_t)gh * W + gw;
#pragma unroll
          for (int co = 0; co < 11; ++co)
            outf[(size_t)(b * 11 + co) * HW + s] = g[co] * inv;
        }

        // ---- stage x stencil window into LDS (exact copies), all threads --
        // xs[c][r][col] : 19 x TR x 34 fp32 = 15504 B (tile = 16320 B)
        float* xs = (float*)tile;
        for (int idx = tid; idx < XN; idx += 256) {
          const int c = idx / (TR * 34);
          const int rem = idx - c * (TR * 34);
          const int r = rem / 34, col = rem - r * 34;
          const int gh2 = h0 + r - 1, gw2 = w0 + col - 1;
          float v = 0.f;
          if ((unsigned)gh2 < (unsigned)H && (unsigned)gw2 < (unsigned)W)
            v = xin[(size_t)(b * 19 + c) * HW + (size_t)gh2 * W + gw2];
          xs[idx] = v;
        }
        __syncthreads();

        if (act) {
          // fused combine for this pixel: gn[m] = g[m]*inv is bit-identical
          // to the fp32 store/load of gfo the standalone kernel did.
          float gn[11];
#pragma unroll
          for (int m = 0; m < 11; ++m) gn[m] = g[m] * inv;
          const int pr = p >> 5, pc = p & 31;
          const unsigned short* ip = ipn + ((size_t)b * HW + s) * 24;
          for (int c = 0; c < 19; ++c) {
            const float* xc = xs + c * (TR * 34);
            const float* x0 = xc + (pr + 0) * 34 + pc;  // row gh-1
            const float* x1 = xc + (pr + 1) * 34 + pc;  // row gh
            const float* x2 = xc + (pr + 2) * 34 + pc;  // row gh+1
            const float itv = bf2f(ip[c]);
            float a = gn[0] * x1[1];
            a = fmaf(gn[1], x0[0], a);
            a = fmaf(gn[2], x0[1], a);
            a = fmaf(gn[3], x0[2], a);
            a = fmaf(gn[4], x1[0], a);
            a = fmaf(gn[5], x1[2], a);
            a = fmaf(gn[6], x2[0], a);
            a = fmaf(gn[7], x2[1], a);
            a = fmaf(gn[8], x2[2], a);
            a = fmaf(gn[10], itv, a);
            outc[(size_t)(b * 19 + c) * HW + s] = a;
          }
        }
      }
    }
  }
}

// ---------------------------------------------------------------------------
extern "C" void kernel_launch(void* const* d_in, const int* in_sizes, int n_in,
                              void* d_out, int out_size, void* d_ws,
                              size_t ws_size, hipStream_t stream) {
  const float* x     = (const float*)d_in[0];
  const float* image = (const float*)d_in[1];
  const float* iw1 = (const float*)d_in[2];
  const float* ib1 = (const float*)d_in[3];
  const float* iw2 = (const float*)d_in[4];
  const float* ib2 = (const float*)d_in[5];
  const float* iw3 = (const float*)d_in[6];
  const float* ib3 = (const float*)d_in[7];
  const float* gw1 = (const float*)d_in[8];
  const float* gb1 = (const float*)d_in[9];
  const float* gw2 = (const float*)d_in[10];
  const float* gb2 = (const float*)d_in[11];
  const float* gw3 = (const float*)d_in[12];
  const float* gb3 = (const float*)d_in[13];

  // Workspace layout in FLOAT units (1 float = 2 bf16):
  //   sx   [  0,   2)*HW   argmax map
  //   f1p  [  2,  18)*HW   [B][H][W][16] bf16
  //   intp [ 34,  58)*HW   [B][H][W][24] bf16
  //   g1p  [ 58,  90)*HW   [B][H][W][32] bf16
  //   bpacks at 122*HW
  float* ws = (float*)d_ws;
  float* sx = ws;
  unsigned short* f1p  = (unsigned short*)(ws + (size_t)2 * HW);
  unsigned short* intp = (unsigned short*)(ws + (size_t)34 * HW);
  unsigned short* g1p  = (unsigned short*)(ws + (size_t)58 * HW);
  unsigned short* bp_ic2 = (unsigned short*)(ws + (size_t)122 * HW);  // 2560
  unsigned short* bp_gc1 = bp_ic2 + 4096;                             // 7168
  unsigned short* bp_gc2 = bp_gc1 + 12288;                            // 9216

  float* out0 = (float*)d_out;               // (2,19,512,512)
  float* gfo  = out0 + (size_t)2 * 19 * HW;  // (2,11,1,512,512)
  float* edg  = gfo + (size_t)2 * 11 * HW;   // (2,1,512,512)

  const dim3 grdM(W / 32, H / 4, B);  // 32x4 tiles -> 4096 blocks

  // 4 dispatches: prelude(argmax+pack+repack), conv16(+1x1),
  // conv24(+edge), conv32(+1x1+combine).
  prelude_kernel<<<2048 + 2048 + 74, 256, 0, stream>>>(
      x, sx, image, iw1, ib1, f1p, iw2, gw1, gw2, bp_ic2, bp_gc1, bp_gc2);

  // intra conv2 (16->16) + fused 1x1 16->19 -> packed intra [H][W][24]
  conv3x3_mfma<16, 5, 1, false, 1><<<grdM, 256, 0, stream>>>(
      f1p, nullptr, bp_ic2, ib2, iw3, ib3, intp, nullptr, nullptr, nullptr, nullptr);
  // guide conv1 (20->32) + inline edge from sx (writes edg output) -> g1p
  conv3x3_mfma<24, 7, 2, true, 0><<<grdM, 256, 0, stream>>>(
      intp, sx, bp_gc1, gb1, nullptr, nullptr, g1p, edg, nullptr, nullptr, nullptr);
  // guide conv2 (32->32) + fused 1x1 32->11 + sigmoid + normalize -> gfo
  // + fused combine (serial LDS-staged x window) -> out0
  conv3x3_mfma<32, 9, 2, false, 3><<<grdM, 256, 0, stream>>>(
      g1p, nullptr, bp_gc2, gb2, gw3, gb3, nullptr, gfo, x, intp, out0);
}